// Round 4
// baseline (1114.769 us; speedup 1.0000x reference)
//
#include <hip/hip_runtime.h>

typedef _Float16 f16;
typedef __attribute__((ext_vector_type(8))) _Float16 half8;
typedef __attribute__((ext_vector_type(4))) float f32x4;

struct f16x4 { f16 a, b, c, d; };

__device__ __forceinline__ void glds16(const f16* g, f16* l) {
  __builtin_amdgcn_global_load_lds(
      (const __attribute__((address_space(1))) void*)g,
      (__attribute__((address_space(3))) void*)l, 16, 0, 0);
}

// ---------------- fp32 -> fp16 hi/lo split (vectorized) ----------------
__global__ void cvt_split(const float* __restrict__ in, f16* __restrict__ hi,
                          f16* __restrict__ lo, long n) {
  long i = ((long)blockIdx.x * blockDim.x + threadIdx.x) * 4;
  if (i >= n) return;
  const float4 v = *(const float4*)(in + i);
  f16x4 h, l;
  h.a = (f16)v.x; l.a = (f16)(v.x - (float)h.a);
  h.b = (f16)v.y; l.b = (f16)(v.y - (float)h.b);
  h.c = (f16)v.z; l.c = (f16)(v.z - (float)h.c);
  h.d = (f16)v.w; l.d = (f16)(v.w - (float)h.d);
  *(f16x4*)(hi + i) = h;
  *(f16x4*)(lo + i) = l;
}

// ---------------- bias_sum[e] = sum_r msg_b[r,e] ----------------
__global__ void bias_sum_k(const float* __restrict__ msg_b, float* __restrict__ bs) {
  int e = threadIdx.x;  // 512 threads
  float s = 0.f;
  for (int r = 0; r < 8; ++r) s += msg_b[r * 512 + e];
  bs[e] = s;
}

// ---------------- split-fp16 MFMA GEMM, B^T pattern, BK=32, swizzled ----------------
// C[m,n] = sum_{r,k} A_r[m,k] * B_r[n,k] (+bias[n]), K=512 per r, lda=ldb=512.
// acc += Ah*Bh [+Ah*Bl if SB] [+Al*Bh if SA].  128x128 tile, 4 waves 2x2.
// LDS: (2+SA+SB)*8KB; 16B chunks XOR-swizzled (uniform 2-way = free, m136).
// Output: Chi/Clo f16 split pair, or Cf fp32.
template <int SA, int SB>
__global__ __launch_bounds__(256) void gemm_sp(
    const f16* __restrict__ Ah, const f16* __restrict__ Al,
    const f16* __restrict__ Bh, const f16* __restrict__ Bl,
    f16* __restrict__ Chi, f16* __restrict__ Clo, float* __restrict__ Cf,
    const float* __restrict__ bias, int N, int R, long sAr, long sBr,
    int zdiv, long sAzr, long sAzb, long sBzr, long sBzb,
    long sCzr, long sCzb) {
  constexpr int OAL = 4096;              // f16 elems per 128x32 tile
  constexpr int OBH = (1 + SA) * 4096;
  constexpr int OBL = OBH + 4096;
  __shared__ __align__(16) f16 smem[(2 + SA + SB) * 4096];

  const int tid = threadIdx.x;
  const int z = blockIdx.z;
  const int zr = z % zdiv, zb = z / zdiv;
  const f16* Abh = Ah + (long)zr * sAzr + (long)zb * sAzb + (long)blockIdx.y * 128 * 512;
  const f16* Bbh = Bh + (long)zr * sBzr + (long)zb * sBzb + (long)blockIdx.x * 128 * 512;
  const f16* Abl = SA ? (Al + (Abh - Ah)) : nullptr;
  const f16* Bbl = SB ? (Bl + (Bbh - Bh)) : nullptr;
  const long cbase = (long)zr * sCzr + (long)zb * sCzb;
  const int lane = tid & 63;
  const int w = tid >> 6;
  const int wm = (w & 1) << 6;
  const int wn = (w >> 1) << 6;

  f32x4 acc[4][4];
#pragma unroll
  for (int i = 0; i < 4; ++i)
#pragma unroll
    for (int j = 0; j < 4; ++j) acc[i][j] = (f32x4){0.f, 0.f, 0.f, 0.f};

  const int l15 = lane & 15;
  // swizzled element offset within a row (wave-constant per lane)
  const int sw = (((lane >> 4) ^ ((l15 >> 1) & 3)) << 3);

  for (int r = 0; r < R; ++r) {
    const long ro = (long)r * sAr;
    const long roB = (long)r * sBr;
    for (int k0 = 0; k0 < 512; k0 += 32) {
#pragma unroll
      for (int i = 0; i < 2; ++i) {
        const int c = i * 256 + tid;                  // LDS slot index (16B units)
        const int kc = (c & 3) ^ ((c >> 3) & 3);      // swizzled global chunk
        const long goff = (long)(c >> 2) * 512 + k0 + kc * 8;
        glds16(Abh + ro + goff, &smem[c * 8]);
        if constexpr (SA) glds16(Abl + ro + goff, &smem[OAL + c * 8]);
        glds16(Bbh + roB + goff, &smem[OBH + c * 8]);
        if constexpr (SB) glds16(Bbl + roB + goff, &smem[OBL + c * 8]);
      }
      __syncthreads();
      half8 ah[4], al[4], bh[4], bl[4];
#pragma unroll
      for (int t = 0; t < 4; ++t) {
        const int ro2 = (wm + t * 16 + l15) * 32 + sw;
        ah[t] = *(const half8*)&smem[ro2];
        if constexpr (SA) al[t] = *(const half8*)&smem[OAL + ro2];
      }
#pragma unroll
      for (int t = 0; t < 4; ++t) {
        const int ro2 = (wn + t * 16 + l15) * 32 + sw;
        bh[t] = *(const half8*)&smem[OBH + ro2];
        if constexpr (SB) bl[t] = *(const half8*)&smem[OBL + ro2];
      }
#pragma unroll
      for (int mt = 0; mt < 4; ++mt)
#pragma unroll
        for (int nt = 0; nt < 4; ++nt) {
          acc[mt][nt] = __builtin_amdgcn_mfma_f32_16x16x32_f16(ah[mt], bh[nt], acc[mt][nt], 0, 0, 0);
          if constexpr (SB)
            acc[mt][nt] = __builtin_amdgcn_mfma_f32_16x16x32_f16(ah[mt], bl[nt], acc[mt][nt], 0, 0, 0);
          if constexpr (SA)
            acc[mt][nt] = __builtin_amdgcn_mfma_f32_16x16x32_f16(al[mt], bh[nt], acc[mt][nt], 0, 0, 0);
        }
      __syncthreads();
    }
  }
  // epilogue: C/D layout col = lane&15, row = (lane>>4)*4 + v  [m89-verified]
  const int rb = (lane >> 4) << 2;
#pragma unroll
  for (int nt = 0; nt < 4; ++nt) {
    const int col = blockIdx.x * 128 + wn + nt * 16 + l15;
    const float bv = bias ? bias[col] : 0.f;
#pragma unroll
    for (int mt = 0; mt < 4; ++mt) {
      const long rowbase = (long)(blockIdx.y * 128 + wm + mt * 16 + rb) * N + col;
#pragma unroll
      for (int v = 0; v < 4; ++v) {
        const float cval = acc[mt][nt][v] + bv;
        const long idx = cbase + rowbase + (long)v * N;
        if (Chi) {
          const f16 h = (f16)cval;
          Chi[idx] = h;
          Clo[idx] = (f16)(cval - (float)h);
        }
        if (Cf) Cf[idx] = cval;
      }
    }
  }
}

// ---------------- split-K x4 reduce: agg = sum_q (Phi_q + Plo_q) + bsum -> f16 hi/lo ----------------
__global__ void reduce_agg4(const f16* __restrict__ Phi, const f16* __restrict__ Plo,
                            const float* __restrict__ bsum,
                            f16* __restrict__ hi, f16* __restrict__ lo) {
  const long i = ((long)blockIdx.x * blockDim.x + threadIdx.x) * 4;  // 4096x256 blocks
  const int col = (int)(i & 511);
  const float4 b = *(const float4*)(bsum + col);
  float v0 = b.x, v1 = b.y, v2 = b.z, v3 = b.w;
#pragma unroll
  for (int q = 0; q < 4; ++q) {
    const long o = (long)q * 4194304 + i;
    const f16x4 ph = *(const f16x4*)(Phi + o);
    const f16x4 pl = *(const f16x4*)(Plo + o);
    v0 += (float)ph.a + (float)pl.a;
    v1 += (float)ph.b + (float)pl.b;
    v2 += (float)ph.c + (float)pl.c;
    v3 += (float)ph.d + (float)pl.d;
  }
  f16x4 h, l;
  h.a = (f16)v0; l.a = (f16)(v0 - (float)h.a);
  h.b = (f16)v1; l.b = (f16)(v1 - (float)h.b);
  h.c = (f16)v2; l.c = (f16)(v2 - (float)h.c);
  h.d = (f16)v3; l.d = (f16)(v3 - (float)h.d);
  *(f16x4*)(hi + i) = h;
  *(f16x4*)(lo + i) = l;
}

// ---------------- GRU elementwise (fp32 gates) ----------------
__global__ void gru_k(const float* __restrict__ gi, const float* __restrict__ gh,
                      const float* __restrict__ holdf,
                      f16* __restrict__ hhi, f16* __restrict__ hlo) {
  const int idx = blockIdx.x * blockDim.x + threadIdx.x;  // 4,194,304 threads
  const int row = idx >> 9, d = idx & 511;
  const long base = (long)row * 1536 + d;
  const float ir = gi[base],         hr = gh[base];
  const float iz = gi[base + 512],   hz = gh[base + 512];
  const float in_ = gi[base + 1024], hn = gh[base + 1024];
  const float h = holdf ? holdf[idx] : ((float)hhi[idx] + (float)hlo[idx]);
  const float r = 1.f / (1.f + __expf(-(ir + hr)));
  const float zg = 1.f / (1.f + __expf(-(iz + hz)));
  const float nt = tanhf(in_ + r * hn);
  const float o = (1.f - zg) * nt + zg * h;
  const f16 oh = (f16)o;
  hhi[idx] = oh;
  hlo[idx] = (f16)(o - (float)oh);
}

// ---------------- mean over nodes ----------------
__global__ void mean_k(const f16* __restrict__ hhi, const f16* __restrict__ hlo,
                       float* __restrict__ out) {
  const int b = blockIdx.x;   // 16
  const int d = threadIdx.x;  // 512
  const long base = (long)b * 512 * 512 + d;
  float s = 0.f;
  for (int i = 0; i < 512; ++i) {
    const long j = base + (long)i * 512;
    s += (float)hhi[j] + (float)hlo[j];
  }
  out[b * 512 + d] = s * (1.f / 512.f);
}

extern "C" void kernel_launch(void* const* d_in, const int* in_sizes, int n_in,
                              void* d_out, int out_size, void* d_ws, size_t ws_size,
                              hipStream_t stream) {
  const float* nodes = (const float*)d_in[0];  // [16,512,512]
  const float* edges = (const float*)d_in[1];  // [16,8,512,512]
  const float* msg_W = (const float*)d_in[2];  // [8,512,512]
  const float* msg_b = (const float*)d_in[3];  // [8,512]
  const float* w_ih  = (const float*)d_in[4];  // [1536,512]
  const float* w_hh  = (const float*)d_in[5];  // [1536,512]
  const float* b_ih  = (const float*)d_in[6];  // [1536]
  const float* b_hh  = (const float*)d_in[7];  // [1536]
  float* out = (float*)d_out;                  // [16,512]

  char* ws = (char*)d_ws;
  size_t off = 0;
  auto alloc = [&](size_t bytes) -> char* {
    char* p = ws + off;
    off += (bytes + 1023) & ~(size_t)1023;
    return p;
  };
  f16* edges_hi = (f16*)alloc(33554432ull * 2);
  f16* edges_lo = (f16*)alloc(33554432ull * 2);
  f16* W_hi     = (f16*)alloc(2097152ull * 2);
  f16* W_lo     = (f16*)alloc(2097152ull * 2);
  f16* wih_hi   = (f16*)alloc(786432ull * 2);
  f16* wih_lo   = (f16*)alloc(786432ull * 2);   // (unused, layout stability)
  f16* whh_hi   = (f16*)alloc(786432ull * 2);
  f16* whh_lo   = (f16*)alloc(786432ull * 2);   // (unused)
  f16* h_hi     = (f16*)alloc(4194304ull * 2);
  f16* h_lo     = (f16*)alloc(4194304ull * 2);
  f16* hWT_hi   = (f16*)alloc(33554432ull * 2);  // head: gi fp32 after G3; tail: agg_hi/lo
  f16* hWT_lo   = (f16*)alloc(33554432ull * 2);  // head: gh fp32 after G4
  f16* Phi      = (f16*)alloc(16777216ull * 2);  // split-K x4 partial hi [q][b][i,e]
  f16* Plo      = (f16*)alloc(16777216ull * 2);  // split-K x4 partial lo
  float* bsum   = (float*)alloc(512 * 4);
  // carve the dead tail of hWT for agg (dead between G2-read and next G1-write):
  float* gi = (float*)hWT_hi;                 // 50.33 MB
  float* gh = (float*)hWT_lo;                 // 50.33 MB
  f16* agg_hi = hWT_hi + 25165824;            // 8.39 MB
  f16* agg_lo = agg_hi + 4194304;             // 8.39 MB (ends exactly at region end)
  // total ws use ~268 MB (less than round-3's 334 MB known-good)

  // one-time converts
  cvt_split<<<32768, 256, 0, stream>>>(edges, edges_hi, edges_lo, 33554432L);
  cvt_split<<<2048,  256, 0, stream>>>(msg_W, W_hi, W_lo, 2097152L);
  cvt_split<<<768,   256, 0, stream>>>(w_ih, wih_hi, wih_lo, 786432L);
  cvt_split<<<768,   256, 0, stream>>>(w_hh, whh_hi, whh_lo, 786432L);
  cvt_split<<<4096,  256, 0, stream>>>(nodes, h_hi, h_lo, 4194304L);
  bias_sum_k<<<1, 512, 0, stream>>>(msg_b, bsum);

  for (int step = 0; step < 2; ++step) {
    // G1: hWT[b*8+r][e,j] = sum_d W[r][e,d] * h[b][j,d]  (split x split)
    //     z = b*8+r: zr=r, zb=b
    gemm_sp<1, 1><<<dim3(4, 4, 128), 256, 0, stream>>>(
        W_hi, W_lo, h_hi, h_lo, hWT_hi, hWT_lo, nullptr, nullptr,
        512, 1, 0L, 0L, 8, 262144L, 0L, 0L, 262144L, 262144L, 2097152L);
    // G2: split-K x4 over relation quarters: z = b*4+q (zr=q, zb=b), R=2
    //     partial[q][b][i,e] -> Phi/Plo f16 pair (22-bit, ~4e-6 abs rounding)
    gemm_sp<1, 1><<<dim3(4, 4, 64), 256, 0, stream>>>(
        edges_hi, edges_lo, hWT_hi, hWT_lo, Phi, Plo, nullptr, nullptr,
        512, 2, 262144L, 262144L, 4, 524288L, 2097152L, 524288L, 2097152L,
        4194304L, 262144L);
    // reduce: agg = sum_q (Phi_q+Plo_q) + bsum -> hi/lo (into hWT tail)
    reduce_agg4<<<4096, 256, 0, stream>>>(Phi, Plo, bsum, agg_hi, agg_lo);
    // G3: gi[i,g] = sum_e agg[i,e] * w_ih[g,e] + b_ih[g]  (split-A, fp32 out)
    gemm_sp<1, 0><<<dim3(12, 64, 1), 256, 0, stream>>>(
        agg_hi, agg_lo, wih_hi, nullptr, nullptr, nullptr, gi, b_ih,
        1536, 1, 0L, 0L, 1, 0L, 0L, 0L, 0L, 0L, 0L);
    // G4: gh[i,g] = sum_d h[i,d] * w_hh[g,d] + b_hh[g]  (single, fp32 out)
    gemm_sp<0, 0><<<dim3(12, 64, 1), 256, 0, stream>>>(
        h_hi, nullptr, whh_hi, nullptr, nullptr, nullptr, gh, b_hh,
        1536, 1, 0L, 0L, 1, 0L, 0L, 0L, 0L, 0L, 0L);
    // GRU update -> h hi/lo (in-place safe: per-thread read-before-write)
    gru_k<<<16384, 256, 0, stream>>>(gi, gh, step ? nullptr : nodes, h_hi, h_lo);
  }
  mean_k<<<16, 512, 0, stream>>>(h_hi, h_lo, out);
}

// Round 5
// 994.324 us; speedup vs baseline: 1.1211x; 1.1211x over previous
//
#include <hip/hip_runtime.h>

typedef _Float16 f16;
typedef __attribute__((ext_vector_type(8))) _Float16 half8;
typedef __attribute__((ext_vector_type(4))) float f32x4;

struct f16x4 { f16 a, b, c, d; };

__device__ __forceinline__ void glds16(const f16* g, f16* l) {
  __builtin_amdgcn_global_load_lds(
      (const __attribute__((address_space(1))) void*)g,
      (__attribute__((address_space(3))) void*)l, 16, 0, 0);
}

// ---------------- fp32 -> fp16 hi/lo split (vectorized) ----------------
__global__ void cvt_split(const float* __restrict__ in, f16* __restrict__ hi,
                          f16* __restrict__ lo, long n) {
  long i = ((long)blockIdx.x * blockDim.x + threadIdx.x) * 4;
  if (i >= n) return;
  const float4 v = *(const float4*)(in + i);
  f16x4 h, l;
  h.a = (f16)v.x; l.a = (f16)(v.x - (float)h.a);
  h.b = (f16)v.y; l.b = (f16)(v.y - (float)h.b);
  h.c = (f16)v.z; l.c = (f16)(v.z - (float)h.c);
  h.d = (f16)v.w; l.d = (f16)(v.w - (float)h.d);
  *(f16x4*)(hi + i) = h;
  *(f16x4*)(lo + i) = l;
}

// ---------------- bias_sum[e] = sum_r msg_b[r,e] ----------------
__global__ void bias_sum_k(const float* __restrict__ msg_b, float* __restrict__ bs) {
  int e = threadIdx.x;  // 512 threads
  float s = 0.f;
  for (int r = 0; r < 8; ++r) s += msg_b[r * 512 + e];
  bs[e] = s;
}

// ---------------- split-fp16 MFMA GEMM, B^T pattern, BK=32, swizzled ----------------
// C[m,n] = sum_{r,k} A_r[m,k] * B_r[n,k] (+bias[n]), K=512 per r, lda=ldb=512.
// acc += Ah*Bh [+Ah*Bl if SB] [+Al*Bh if SA].  128x128 tile, 4 waves 2x2.
// LDS: (2+SA+SB)*8KB; 16B chunks XOR-swizzled (uniform 2-way = free, m136).
// SA&&SB -> f16 hi/lo pair output via LDS-staged vectorized epilogue.
// else   -> fp32 direct output.
// SWZ: flat grid, z-slice-per-XCD remap for L2 locality.
template <int SA, int SB, int SWZ>
__global__ __launch_bounds__(256) void gemm_sp(
    const f16* __restrict__ Ah, const f16* __restrict__ Al,
    const f16* __restrict__ Bh, const f16* __restrict__ Bl,
    f16* __restrict__ Chi, f16* __restrict__ Clo, float* __restrict__ Cf,
    const float* __restrict__ bias, int N, int R, long sAr, long sBr,
    int zdiv, long sAzr, long sAzb, long sBzr, long sBzb,
    long sCzr, long sCzb) {
  constexpr int OAL = 4096;              // f16 elems per 128x32 tile
  constexpr int OBH = (1 + SA) * 4096;
  constexpr int OBL = OBH + 4096;
  __shared__ __align__(16) f16 smem[(2 + SA + SB) * 4096];

  const int tid = threadIdx.x;
  int bx, by, z;
  if constexpr (SWZ) {
    // all 16 (bx,by) blocks of one z-slice -> consecutive-by-8 linear ids
    // -> one XCD under round-robin dispatch; z == xcd (mod 8).
    const int l = blockIdx.x;
    const int xcd = l & 7, m2 = l >> 3, zq = m2 >> 4, t = m2 & 15;
    z = (zq << 3) | xcd; bx = t & 3; by = t >> 2;
  } else {
    bx = blockIdx.x; by = blockIdx.y; z = blockIdx.z;
  }
  const int zr = z % zdiv, zb = z / zdiv;
  const f16* Abh = Ah + (long)zr * sAzr + (long)zb * sAzb + (long)by * 128 * 512;
  const f16* Bbh = Bh + (long)zr * sBzr + (long)zb * sBzb + (long)bx * 128 * 512;
  const f16* Abl = SA ? (Al + (Abh - Ah)) : nullptr;
  const f16* Bbl = SB ? (Bl + (Bbh - Bh)) : nullptr;
  const long cbase = (long)zr * sCzr + (long)zb * sCzb;
  const int lane = tid & 63;
  const int w = tid >> 6;
  const int wm = (w & 1) << 6;
  const int wn = (w >> 1) << 6;

  f32x4 acc[4][4];
#pragma unroll
  for (int i = 0; i < 4; ++i)
#pragma unroll
    for (int j = 0; j < 4; ++j) acc[i][j] = (f32x4){0.f, 0.f, 0.f, 0.f};

  const int l15 = lane & 15;
  // swizzled element offset within a row (wave-constant per lane)
  const int sw = (((lane >> 4) ^ ((l15 >> 1) & 3)) << 3);

  for (int r = 0; r < R; ++r) {
    const long ro = (long)r * sAr;
    const long roB = (long)r * sBr;
    for (int k0 = 0; k0 < 512; k0 += 32) {
#pragma unroll
      for (int i = 0; i < 2; ++i) {
        const int c = i * 256 + tid;                  // LDS slot index (16B units)
        const int kc = (c & 3) ^ ((c >> 3) & 3);      // swizzled global chunk
        const long goff = (long)(c >> 2) * 512 + k0 + kc * 8;
        glds16(Abh + ro + goff, &smem[c * 8]);
        if constexpr (SA) glds16(Abl + ro + goff, &smem[OAL + c * 8]);
        glds16(Bbh + roB + goff, &smem[OBH + c * 8]);
        if constexpr (SB) glds16(Bbl + roB + goff, &smem[OBL + c * 8]);
      }
      __syncthreads();
      half8 ah[4], al[4], bh[4], bl[4];
#pragma unroll
      for (int t = 0; t < 4; ++t) {
        const int ro2 = (wm + t * 16 + l15) * 32 + sw;
        ah[t] = *(const half8*)&smem[ro2];
        if constexpr (SA) al[t] = *(const half8*)&smem[OAL + ro2];
      }
#pragma unroll
      for (int t = 0; t < 4; ++t) {
        const int ro2 = (wn + t * 16 + l15) * 32 + sw;
        bh[t] = *(const half8*)&smem[OBH + ro2];
        if constexpr (SB) bl[t] = *(const half8*)&smem[OBL + ro2];
      }
#pragma unroll
      for (int mt = 0; mt < 4; ++mt)
#pragma unroll
        for (int nt = 0; nt < 4; ++nt) {
          acc[mt][nt] = __builtin_amdgcn_mfma_f32_16x16x32_f16(ah[mt], bh[nt], acc[mt][nt], 0, 0, 0);
          if constexpr (SB)
            acc[mt][nt] = __builtin_amdgcn_mfma_f32_16x16x32_f16(ah[mt], bl[nt], acc[mt][nt], 0, 0, 0);
          if constexpr (SA)
            acc[mt][nt] = __builtin_amdgcn_mfma_f32_16x16x32_f16(al[mt], bh[nt], acc[mt][nt], 0, 0, 0);
        }
      __syncthreads();
    }
  }
  // epilogue: C/D layout col = lane&15, row = (lane>>4)*4 + v  [m89-verified]
  const int rb = (lane >> 4) << 2;
  if constexpr (SA && SB) {
    // LDS-staged f16 hi/lo pair output (smem is free & exactly 128x128 f16).
    // Stage with 16B-granule XOR swizzle pg = lg ^ (row&15) -> conflict-free
    // read-back; cooperative dwordx4 stores (8 per thread per pass).
    const int srow = tid >> 1, shalf = tid & 1;     // coop-store mapping
    // pass 1: hi (and turn acc into the residual)
#pragma unroll
    for (int nt = 0; nt < 4; ++nt) {
      const int col = wn + nt * 16 + l15;
      const float bv = bias ? bias[bx * 128 + col] : 0.f;
#pragma unroll
      for (int mt = 0; mt < 4; ++mt)
#pragma unroll
        for (int v = 0; v < 4; ++v) {
          const int row = wm + mt * 16 + rb + v;
          const float cval = acc[mt][nt][v] + bv;
          const f16 h = (f16)cval;
          smem[row * 128 + ((col >> 3) ^ (row & 15)) * 8 + (col & 7)] = h;
          acc[mt][nt][v] = cval - (float)h;
        }
    }
    __syncthreads();
#pragma unroll
    for (int u = 0; u < 8; ++u) {
      const int lg = shalf * 8 + u;
      const int pg = lg ^ (srow & 15);
      const int4 vv = *(const int4*)&smem[srow * 128 + pg * 8];
      *(int4*)&Chi[cbase + (long)(by * 128 + srow) * N + bx * 128 + lg * 8] = vv;
    }
    __syncthreads();
    // pass 2: lo from residual
#pragma unroll
    for (int nt = 0; nt < 4; ++nt) {
      const int col = wn + nt * 16 + l15;
#pragma unroll
      for (int mt = 0; mt < 4; ++mt)
#pragma unroll
        for (int v = 0; v < 4; ++v) {
          const int row = wm + mt * 16 + rb + v;
          smem[row * 128 + ((col >> 3) ^ (row & 15)) * 8 + (col & 7)] =
              (f16)acc[mt][nt][v];
        }
    }
    __syncthreads();
#pragma unroll
    for (int u = 0; u < 8; ++u) {
      const int lg = shalf * 8 + u;
      const int pg = lg ^ (srow & 15);
      const int4 vv = *(const int4*)&smem[srow * 128 + pg * 8];
      *(int4*)&Clo[cbase + (long)(by * 128 + srow) * N + bx * 128 + lg * 8] = vv;
    }
  } else {
    // fp32 direct output
#pragma unroll
    for (int nt = 0; nt < 4; ++nt) {
      const int col = bx * 128 + wn + nt * 16 + l15;
      const float bv = bias ? bias[col] : 0.f;
#pragma unroll
      for (int mt = 0; mt < 4; ++mt) {
        const long rowbase = (long)(by * 128 + wm + mt * 16 + rb) * N + col;
#pragma unroll
        for (int v = 0; v < 4; ++v)
          Cf[cbase + rowbase + (long)v * N] = acc[mt][nt][v] + bv;
      }
    }
  }
}

// ---------------- split-K x4 reduce: agg = sum_q (Phi_q + Plo_q) + bsum -> f16 hi/lo ----------------
__global__ void reduce_agg4(const f16* __restrict__ Phi, const f16* __restrict__ Plo,
                            const float* __restrict__ bsum,
                            f16* __restrict__ hi, f16* __restrict__ lo) {
  const long i = ((long)blockIdx.x * blockDim.x + threadIdx.x) * 4;  // 4096x256 blocks
  const int col = (int)(i & 511);
  const float4 b = *(const float4*)(bsum + col);
  float v0 = b.x, v1 = b.y, v2 = b.z, v3 = b.w;
#pragma unroll
  for (int q = 0; q < 4; ++q) {
    const long o = (long)q * 4194304 + i;
    const f16x4 ph = *(const f16x4*)(Phi + o);
    const f16x4 pl = *(const f16x4*)(Plo + o);
    v0 += (float)ph.a + (float)pl.a;
    v1 += (float)ph.b + (float)pl.b;
    v2 += (float)ph.c + (float)pl.c;
    v3 += (float)ph.d + (float)pl.d;
  }
  f16x4 h, l;
  h.a = (f16)v0; l.a = (f16)(v0 - (float)h.a);
  h.b = (f16)v1; l.b = (f16)(v1 - (float)h.b);
  h.c = (f16)v2; l.c = (f16)(v2 - (float)h.c);
  h.d = (f16)v3; l.d = (f16)(v3 - (float)h.d);
  *(f16x4*)(hi + i) = h;
  *(f16x4*)(lo + i) = l;
}

// ---------------- GRU elementwise (fp32 gates) ----------------
__global__ void gru_k(const float* __restrict__ gi, const float* __restrict__ gh,
                      const float* __restrict__ holdf,
                      f16* __restrict__ hhi, f16* __restrict__ hlo) {
  const int idx = blockIdx.x * blockDim.x + threadIdx.x;  // 4,194,304 threads
  const int row = idx >> 9, d = idx & 511;
  const long base = (long)row * 1536 + d;
  const float ir = gi[base],         hr = gh[base];
  const float iz = gi[base + 512],   hz = gh[base + 512];
  const float in_ = gi[base + 1024], hn = gh[base + 1024];
  const float h = holdf ? holdf[idx] : ((float)hhi[idx] + (float)hlo[idx]);
  const float r = 1.f / (1.f + __expf(-(ir + hr)));
  const float zg = 1.f / (1.f + __expf(-(iz + hz)));
  const float nt = tanhf(in_ + r * hn);
  const float o = (1.f - zg) * nt + zg * h;
  const f16 oh = (f16)o;
  hhi[idx] = oh;
  hlo[idx] = (f16)(o - (float)oh);
}

// ---------------- mean over nodes ----------------
__global__ void mean_k(const f16* __restrict__ hhi, const f16* __restrict__ hlo,
                       float* __restrict__ out) {
  const int b = blockIdx.x;   // 16
  const int d = threadIdx.x;  // 512
  const long base = (long)b * 512 * 512 + d;
  float s = 0.f;
  for (int i = 0; i < 512; ++i) {
    const long j = base + (long)i * 512;
    s += (float)hhi[j] + (float)hlo[j];
  }
  out[b * 512 + d] = s * (1.f / 512.f);
}

extern "C" void kernel_launch(void* const* d_in, const int* in_sizes, int n_in,
                              void* d_out, int out_size, void* d_ws, size_t ws_size,
                              hipStream_t stream) {
  const float* nodes = (const float*)d_in[0];  // [16,512,512]
  const float* edges = (const float*)d_in[1];  // [16,8,512,512]
  const float* msg_W = (const float*)d_in[2];  // [8,512,512]
  const float* msg_b = (const float*)d_in[3];  // [8,512]
  const float* w_ih  = (const float*)d_in[4];  // [1536,512]
  const float* w_hh  = (const float*)d_in[5];  // [1536,512]
  const float* b_ih  = (const float*)d_in[6];  // [1536]
  const float* b_hh  = (const float*)d_in[7];  // [1536]
  float* out = (float*)d_out;                  // [16,512]

  char* ws = (char*)d_ws;
  size_t off = 0;
  auto alloc = [&](size_t bytes) -> char* {
    char* p = ws + off;
    off += (bytes + 1023) & ~(size_t)1023;
    return p;
  };
  f16* edges_hi = (f16*)alloc(33554432ull * 2);
  f16* edges_lo = (f16*)alloc(33554432ull * 2);
  f16* W_hi     = (f16*)alloc(2097152ull * 2);
  f16* W_lo     = (f16*)alloc(2097152ull * 2);
  f16* wih_hi   = (f16*)alloc(786432ull * 2);
  f16* wih_lo   = (f16*)alloc(786432ull * 2);   // (unused, layout stability)
  f16* whh_hi   = (f16*)alloc(786432ull * 2);
  f16* whh_lo   = (f16*)alloc(786432ull * 2);   // (unused)
  f16* h_hi     = (f16*)alloc(4194304ull * 2);
  f16* h_lo     = (f16*)alloc(4194304ull * 2);
  f16* hWT_hi   = (f16*)alloc(33554432ull * 2);  // head: gi fp32 after G3; tail: agg_hi/lo
  f16* hWT_lo   = (f16*)alloc(33554432ull * 2);  // head: gh fp32 after G4
  f16* Phi      = (f16*)alloc(16777216ull * 2);  // split-K x4 partial hi [q][b][i,e]
  f16* Plo      = (f16*)alloc(16777216ull * 2);  // split-K x4 partial lo
  float* bsum   = (float*)alloc(512 * 4);
  // carve the dead tail of hWT for agg (dead between G2-read and next G1-write):
  float* gi = (float*)hWT_hi;                 // 50.33 MB
  float* gh = (float*)hWT_lo;                 // 50.33 MB
  f16* agg_hi = hWT_hi + 25165824;            // 8.39 MB
  f16* agg_lo = agg_hi + 4194304;             // 8.39 MB (ends exactly at region end)
  // total ws use ~268 MB

  // one-time converts
  cvt_split<<<32768, 256, 0, stream>>>(edges, edges_hi, edges_lo, 33554432L);
  cvt_split<<<2048,  256, 0, stream>>>(msg_W, W_hi, W_lo, 2097152L);
  cvt_split<<<768,   256, 0, stream>>>(w_ih, wih_hi, wih_lo, 786432L);
  cvt_split<<<768,   256, 0, stream>>>(w_hh, whh_hi, whh_lo, 786432L);
  cvt_split<<<4096,  256, 0, stream>>>(nodes, h_hi, h_lo, 4194304L);
  bias_sum_k<<<1, 512, 0, stream>>>(msg_b, bsum);

  for (int step = 0; step < 2; ++step) {
    // G1: hWT[b*8+r][e,j] = sum_d W[r][e,d] * h[b][j,d]  (split x split)
    //     z = b*8+r: zr=r, zb=b
    gemm_sp<1, 1, 0><<<dim3(4, 4, 128), 256, 0, stream>>>(
        W_hi, W_lo, h_hi, h_lo, hWT_hi, hWT_lo, nullptr, nullptr,
        512, 1, 0L, 0L, 8, 262144L, 0L, 0L, 262144L, 262144L, 2097152L);
    // G2: split-K x4 over relation quarters: z = b*4+q (zr=q, zb=b), R=2
    //     flat grid + XCD swizzle: one z-slice's 16 blocks -> one XCD's L2
    gemm_sp<1, 1, 1><<<dim3(1024, 1, 1), 256, 0, stream>>>(
        edges_hi, edges_lo, hWT_hi, hWT_lo, Phi, Plo, nullptr, nullptr,
        512, 2, 262144L, 262144L, 4, 524288L, 2097152L, 524288L, 2097152L,
        4194304L, 262144L);
    // reduce: agg = sum_q (Phi_q+Plo_q) + bsum -> hi/lo (into hWT tail)
    reduce_agg4<<<4096, 256, 0, stream>>>(Phi, Plo, bsum, agg_hi, agg_lo);
    // G3: gi[i,g] = sum_e agg[i,e] * w_ih[g,e] + b_ih[g]  (split-A, fp32 out)
    gemm_sp<1, 0, 0><<<dim3(12, 64, 1), 256, 0, stream>>>(
        agg_hi, agg_lo, wih_hi, nullptr, nullptr, nullptr, gi, b_ih,
        1536, 1, 0L, 0L, 1, 0L, 0L, 0L, 0L, 0L, 0L);
    // G4: gh[i,g] = sum_d h[i,d] * w_hh[g,d] + b_hh[g]  (single, fp32 out)
    gemm_sp<0, 0, 0><<<dim3(12, 64, 1), 256, 0, stream>>>(
        h_hi, nullptr, whh_hi, nullptr, nullptr, nullptr, gh, b_hh,
        1536, 1, 0L, 0L, 1, 0L, 0L, 0L, 0L, 0L, 0L);
    // GRU update -> h hi/lo (in-place safe: per-thread read-before-write)
    gru_k<<<16384, 256, 0, stream>>>(gi, gh, step ? nullptr : nodes, h_hi, h_lo);
  }
  mean_k<<<16, 512, 0, stream>>>(h_hi, h_lo, out);
}

// Round 6
// 960.092 us; speedup vs baseline: 1.1611x; 1.0357x over previous
//
#include <hip/hip_runtime.h>

typedef _Float16 f16;
typedef __attribute__((ext_vector_type(8))) _Float16 half8;
typedef __attribute__((ext_vector_type(4))) float f32x4;

struct f16x4 { f16 a, b, c, d; };

// frag-major layout for tensor[row][k] with K=512:
//   flat f16 idx = (rt*16 + kc)*512 + l*8 + e
//   row = rt*16 + (l&15), k = kc*32 + (l>>4)*8 + e
// One MFMA fragment = one 16B unit at lane l -> fully coalesced wave loads.

// ---------------- fp32 -> frag-major f16 hi/lo split ----------------
__global__ void cvt_fr(const float* __restrict__ in, f16* __restrict__ hi,
                       f16* __restrict__ lo, int n_units) {
  const int u = blockIdx.x * blockDim.x + threadIdx.x;
  if (u >= n_units) return;
  const int l = u & 63, kc = (u >> 6) & 15, rt = u >> 10;
  const long ibase = (long)(rt * 16 + (l & 15)) * 512 + kc * 32 + ((l >> 4) << 3);
  const float4 v0 = *(const float4*)(in + ibase);
  const float4 v1 = *(const float4*)(in + ibase + 4);
  const float v[8] = {v0.x, v0.y, v0.z, v0.w, v1.x, v1.y, v1.z, v1.w};
  half8 h, lw;
#pragma unroll
  for (int e = 0; e < 8; ++e) {
    h[e] = (f16)v[e];
    lw[e] = (f16)(v[e] - (float)h[e]);
  }
  *(half8*)(hi + (long)u * 8) = h;
  *(half8*)(lo + (long)u * 8) = lw;
}

// ---------------- bias_sum[e] = sum_r msg_b[r,e] ----------------
__global__ void bias_sum_k(const float* __restrict__ msg_b, float* __restrict__ bs) {
  int e = threadIdx.x;  // 512 threads
  float s = 0.f;
  for (int r = 0; r < 8; ++r) s += msg_b[r * 512 + e];
  bs[e] = s;
}

// ---------------- barrier-free direct-register split-f16 MFMA GEMM ----------------
// C[m,n] = sum_{r,k} A_r[m,k]*B_r[n,k]; A,B frag-major (K=512/r-slice).
// acc += Ah*Bh [+Ah*Bl if SB] [+Al*Bh if SA]. 128x128 tile, 4 waves 2x2.
// K-loop: fragments loaded global->VGPR, double-buffered 1 iter ahead,
// NO __syncthreads / NO LDS in the loop (counted-vmcnt pipeline).
// SA&&SB: Chi/Clo frag-major pair out (LDS-staged). else: Cf fp32 linear.
template <int SA, int SB, int SWZ>
__global__ __launch_bounds__(256, 2) void gemm_dr(
    const f16* __restrict__ Ah, const f16* __restrict__ Al,
    const f16* __restrict__ Bh, const f16* __restrict__ Bl,
    f16* __restrict__ Chi, f16* __restrict__ Clo, float* __restrict__ Cf,
    const float* __restrict__ bias, int N, int R, long sAr, long sBr,
    int zdiv, long sAzr, long sAzb, long sBzr, long sBzb,
    long sCzr, long sCzb) {
  __shared__ __align__(16) f16 smem[16384];  // epilogue staging only
  const int tid = threadIdx.x;
  int bx, by, z;
  if constexpr (SWZ) {
    const int l = blockIdx.x;
    const int xcd = l & 7, m2 = l >> 3, zq = m2 >> 4, t = m2 & 15;
    z = (zq << 3) | xcd; bx = t & 3; by = t >> 2;
  } else {
    bx = blockIdx.x; by = blockIdx.y; z = blockIdx.z;
  }
  const int zr = z % zdiv, zb = z / zdiv;
  const int lane = tid & 63;
  const int w = tid >> 6;
  const int wm = (w & 1) << 6;
  const int wn = (w >> 1) << 6;

  const f16* pAh = Ah + (long)zr * sAzr + (long)zb * sAzb +
                   (long)(by * 8 + (wm >> 4)) * 8192 + lane * 8;
  const f16* pBh = Bh + (long)zr * sBzr + (long)zb * sBzb +
                   (long)(bx * 8 + (wn >> 4)) * 8192 + lane * 8;
  const f16* pAl = SA ? (Al + (pAh - Ah)) : nullptr;
  const f16* pBl = SB ? (Bl + (pBh - Bh)) : nullptr;
  const long cbase = (long)zr * sCzr + (long)zb * sCzb;

  f32x4 acc[4][4];
#pragma unroll
  for (int i = 0; i < 4; ++i)
#pragma unroll
    for (int j = 0; j < 4; ++j) acc[i][j] = (f32x4){0.f, 0.f, 0.f, 0.f};

  half8 fAh[2][4], fAl[2][4], fBh[2][4], fBl[2][4];
  const int NIT = R * 16;

  auto LD = [&](int bf, int ii) {
    const int r_ = ii >> 4, kc_ = ii & 15;
    const long oa = (long)r_ * sAr + kc_ * 512;
    const long ob = (long)r_ * sBr + kc_ * 512;
#pragma unroll
    for (int t = 0; t < 4; ++t) {
      fAh[bf][t] = *(const half8*)(pAh + t * 8192 + oa);
      if constexpr (SA) fAl[bf][t] = *(const half8*)(pAl + t * 8192 + oa);
      fBh[bf][t] = *(const half8*)(pBh + t * 8192 + ob);
      if constexpr (SB) fBl[bf][t] = *(const half8*)(pBl + t * 8192 + ob);
    }
  };
  auto MM = [&](int bf) {
#pragma unroll
    for (int mt = 0; mt < 4; ++mt)
#pragma unroll
      for (int nt = 0; nt < 4; ++nt) {
        acc[mt][nt] = __builtin_amdgcn_mfma_f32_16x16x32_f16(
            fAh[bf][mt], fBh[bf][nt], acc[mt][nt], 0, 0, 0);
        if constexpr (SB)
          acc[mt][nt] = __builtin_amdgcn_mfma_f32_16x16x32_f16(
              fAh[bf][mt], fBl[bf][nt], acc[mt][nt], 0, 0, 0);
        if constexpr (SA)
          acc[mt][nt] = __builtin_amdgcn_mfma_f32_16x16x32_f16(
              fAl[bf][mt], fBh[bf][nt], acc[mt][nt], 0, 0, 0);
      }
  };

  LD(0, 0);
  for (int i = 0; i < NIT; i += 2) {
    if (i + 1 < NIT) LD(1, i + 1);
    MM(0);
    if (i + 2 < NIT) LD(0, i + 2);
    if (i + 1 < NIT) MM(1);
  }

  // epilogue: C/D layout col = lane&15, row = (lane>>4)*4 + v  [m89-verified]
  const int l15 = lane & 15;
  const int rb = (lane >> 4) << 2;
  if constexpr (SA && SB) {
    // frag-major f16 hi/lo pair out via LDS re-stage (write swizzle
    // pg = (col>>3)^(row&15); readback granule matches).
    // pass 1: hi (turn acc into residual)
#pragma unroll
    for (int nt = 0; nt < 4; ++nt) {
      const int col = wn + nt * 16 + l15;
#pragma unroll
      for (int mt = 0; mt < 4; ++mt)
#pragma unroll
        for (int v = 0; v < 4; ++v) {
          const int row = wm + mt * 16 + rb + v;
          const float cval = acc[mt][nt][v];
          const f16 h = (f16)cval;
          smem[row * 128 + ((col >> 3) ^ (row & 15)) * 8 + (col & 7)] = h;
          acc[mt][nt][v] = cval - (float)h;
        }
    }
    __syncthreads();
#pragma unroll
    for (int i2 = 0; i2 < 8; ++i2) {
      const int u = i2 * 256 + tid;
      const int ul = u & 63, kc_loc = (u >> 6) & 3, rt_loc = u >> 8;
      const int row = rt_loc * 16 + (ul & 15);
      const int gcol = kc_loc * 4 + (ul >> 4);
      const int4 vv = *(const int4*)&smem[row * 128 + ((gcol ^ (row & 15)) << 3)];
      *(int4*)&Chi[cbase + ((long)(by * 8 + rt_loc) * 16 + bx * 4 + kc_loc) * 512 + ul * 8] = vv;
    }
    __syncthreads();
    // pass 2: lo
#pragma unroll
    for (int nt = 0; nt < 4; ++nt) {
      const int col = wn + nt * 16 + l15;
#pragma unroll
      for (int mt = 0; mt < 4; ++mt)
#pragma unroll
        for (int v = 0; v < 4; ++v) {
          const int row = wm + mt * 16 + rb + v;
          smem[row * 128 + ((col >> 3) ^ (row & 15)) * 8 + (col & 7)] = (f16)acc[mt][nt][v];
        }
    }
    __syncthreads();
#pragma unroll
    for (int i2 = 0; i2 < 8; ++i2) {
      const int u = i2 * 256 + tid;
      const int ul = u & 63, kc_loc = (u >> 6) & 3, rt_loc = u >> 8;
      const int row = rt_loc * 16 + (ul & 15);
      const int gcol = kc_loc * 4 + (ul >> 4);
      const int4 vv = *(const int4*)&smem[row * 128 + ((gcol ^ (row & 15)) << 3)];
      *(int4*)&Clo[cbase + ((long)(by * 8 + rt_loc) * 16 + bx * 4 + kc_loc) * 512 + ul * 8] = vv;
    }
  } else {
    // fp32 direct output (linear rows x N)
#pragma unroll
    for (int nt = 0; nt < 4; ++nt) {
      const int col = bx * 128 + wn + nt * 16 + l15;
      const float bv = bias ? bias[col] : 0.f;
#pragma unroll
      for (int mt = 0; mt < 4; ++mt) {
        const long rowbase = (long)(by * 128 + wm + mt * 16 + rb) * N + col;
#pragma unroll
        for (int v = 0; v < 4; ++v)
          Cf[cbase + rowbase + (long)v * N] = acc[mt][nt][v] + bv;
      }
    }
  }
}

// ---------------- split-K x4 reduce (frag-major): agg = sum_q(Phi+Plo)+bsum ----------------
__global__ void reduce_agg4(const f16* __restrict__ Phi, const f16* __restrict__ Plo,
                            const float* __restrict__ bsum,
                            f16* __restrict__ hi, f16* __restrict__ lo) {
  const long i = ((long)blockIdx.x * blockDim.x + threadIdx.x) * 4;  // 4096x256 blocks
  // frag-major: e = kc*32 + (l>>4)*8 + e8 ; group of 4 stays in one unit
  const int li = (int)i;
  const int l = (li >> 3) & 63, kc = (li >> 9) & 15;
  const int e0 = kc * 32 + ((l >> 4) << 3) + (li & 4);
  const float4 b = *(const float4*)(bsum + e0);
  float v0 = b.x, v1 = b.y, v2 = b.z, v3 = b.w;
#pragma unroll
  for (int q = 0; q < 4; ++q) {
    const long o = (long)q * 4194304 + i;
    const f16x4 ph = *(const f16x4*)(Phi + o);
    const f16x4 pl = *(const f16x4*)(Plo + o);
    v0 += (float)ph.a + (float)pl.a;
    v1 += (float)ph.b + (float)pl.b;
    v2 += (float)ph.c + (float)pl.c;
    v3 += (float)ph.d + (float)pl.d;
  }
  f16x4 h, lw;
  h.a = (f16)v0; lw.a = (f16)(v0 - (float)h.a);
  h.b = (f16)v1; lw.b = (f16)(v1 - (float)h.b);
  h.c = (f16)v2; lw.c = (f16)(v2 - (float)h.c);
  h.d = (f16)v3; lw.d = (f16)(v3 - (float)h.d);
  *(f16x4*)(hi + i) = h;
  *(f16x4*)(lo + i) = lw;
}

// ---------------- GRU elementwise (fp32 gates), h in frag-major hi/lo ----------------
__global__ void gru_k(const float* __restrict__ gi, const float* __restrict__ gh,
                      const float* __restrict__ holdf,
                      f16* __restrict__ hhi, f16* __restrict__ hlo) {
  const int u = blockIdx.x * blockDim.x + threadIdx.x;  // 524288 threads
  const int row = u >> 6, d0 = (u & 63) << 3;
  const long gbase = (long)row * 1536 + d0;
  const float4 giR0 = *(const float4*)(gi + gbase),      giR1 = *(const float4*)(gi + gbase + 4);
  const float4 giZ0 = *(const float4*)(gi + gbase + 512), giZ1 = *(const float4*)(gi + gbase + 516);
  const float4 giN0 = *(const float4*)(gi + gbase + 1024), giN1 = *(const float4*)(gi + gbase + 1028);
  const float4 ghR0 = *(const float4*)(gh + gbase),      ghR1 = *(const float4*)(gh + gbase + 4);
  const float4 ghZ0 = *(const float4*)(gh + gbase + 512), ghZ1 = *(const float4*)(gh + gbase + 516);
  const float4 ghN0 = *(const float4*)(gh + gbase + 1024), ghN1 = *(const float4*)(gh + gbase + 1028);
  const float irv[8] = {giR0.x, giR0.y, giR0.z, giR0.w, giR1.x, giR1.y, giR1.z, giR1.w};
  const float izv[8] = {giZ0.x, giZ0.y, giZ0.z, giZ0.w, giZ1.x, giZ1.y, giZ1.z, giZ1.w};
  const float inv[8] = {giN0.x, giN0.y, giN0.z, giN0.w, giN1.x, giN1.y, giN1.z, giN1.w};
  const float hrv[8] = {ghR0.x, ghR0.y, ghR0.z, ghR0.w, ghR1.x, ghR1.y, ghR1.z, ghR1.w};
  const float hzv[8] = {ghZ0.x, ghZ0.y, ghZ0.z, ghZ0.w, ghZ1.x, ghZ1.y, ghZ1.z, ghZ1.w};
  const float hnv[8] = {ghN0.x, ghN0.y, ghN0.z, ghN0.w, ghN1.x, ghN1.y, ghN1.z, ghN1.w};
  // frag-major address of the 8-elem unit (d0 is 8-aligned)
  const long hflat = (long)(row >> 4) * 8192 + (d0 >> 5) * 512 +
                     ((row & 15) + (((d0 >> 3) & 3) << 4)) * 8;
  half8 hh8, hl8;
  if (!holdf) { hh8 = *(const half8*)(hhi + hflat); hl8 = *(const half8*)(hlo + hflat); }
  half8 oh, ol;
#pragma unroll
  for (int e = 0; e < 8; ++e) {
    const float h = holdf ? holdf[(long)row * 512 + d0 + e]
                          : ((float)hh8[e] + (float)hl8[e]);
    const float r = 1.f / (1.f + __expf(-(irv[e] + hrv[e])));
    const float zg = 1.f / (1.f + __expf(-(izv[e] + hzv[e])));
    const float nt = tanhf(inv[e] + r * hnv[e]);
    const float o = (1.f - zg) * nt + zg * h;
    oh[e] = (f16)o;
    ol[e] = (f16)(o - (float)oh[e]);
  }
  *(half8*)(hhi + hflat) = oh;
  *(half8*)(hlo + hflat) = ol;
}

// ---------------- mean over nodes (h frag-major) ----------------
__global__ void mean_k(const f16* __restrict__ hhi, const f16* __restrict__ hlo,
                       float* __restrict__ out) {
  const int b = blockIdx.x;   // 16
  const int d = threadIdx.x;  // 512
  const long base = (long)b * 262144 + (d >> 5) * 512 + (((d >> 3) & 3) << 4) * 8 + (d & 7);
  float s = 0.f;
  for (int n = 0; n < 512; ++n) {
    const long j = base + (long)(n >> 4) * 8192 + (n & 15) * 8;
    s += (float)hhi[j] + (float)hlo[j];
  }
  out[b * 512 + d] = s * (1.f / 512.f);
}

extern "C" void kernel_launch(void* const* d_in, const int* in_sizes, int n_in,
                              void* d_out, int out_size, void* d_ws, size_t ws_size,
                              hipStream_t stream) {
  const float* nodes = (const float*)d_in[0];  // [16,512,512]
  const float* edges = (const float*)d_in[1];  // [16,8,512,512]
  const float* msg_W = (const float*)d_in[2];  // [8,512,512]
  const float* msg_b = (const float*)d_in[3];  // [8,512]
  const float* w_ih  = (const float*)d_in[4];  // [1536,512]
  const float* w_hh  = (const float*)d_in[5];  // [1536,512]
  const float* b_ih  = (const float*)d_in[6];  // [1536]
  const float* b_hh  = (const float*)d_in[7];  // [1536]
  float* out = (float*)d_out;                  // [16,512]

  char* ws = (char*)d_ws;
  size_t off = 0;
  auto alloc = [&](size_t bytes) -> char* {
    char* p = ws + off;
    off += (bytes + 1023) & ~(size_t)1023;
    return p;
  };
  f16* edges_hi = (f16*)alloc(33554432ull * 2);
  f16* edges_lo = (f16*)alloc(33554432ull * 2);
  f16* W_hi     = (f16*)alloc(2097152ull * 2);
  f16* W_lo     = (f16*)alloc(2097152ull * 2);
  f16* wih_hi   = (f16*)alloc(786432ull * 2);
  f16* wih_lo   = (f16*)alloc(786432ull * 2);   // (unused, layout stability)
  f16* whh_hi   = (f16*)alloc(786432ull * 2);
  f16* whh_lo   = (f16*)alloc(786432ull * 2);   // (unused)
  f16* h_hi     = (f16*)alloc(4194304ull * 2);
  f16* h_lo     = (f16*)alloc(4194304ull * 2);
  f16* hWT_hi   = (f16*)alloc(33554432ull * 2);  // head: gi fp32 after G3; tail: agg_hi/lo
  f16* hWT_lo   = (f16*)alloc(33554432ull * 2);  // head: gh fp32 after G4
  f16* Phi      = (f16*)alloc(16777216ull * 2);  // split-K x4 partial hi [q][b][frag-major]
  f16* Plo      = (f16*)alloc(16777216ull * 2);
  float* bsum   = (float*)alloc(512 * 4);
  float* gi = (float*)hWT_hi;                 // 50.33 MB
  float* gh = (float*)hWT_lo;                 // 50.33 MB
  f16* agg_hi = hWT_hi + 25165824;            // 8.39 MB
  f16* agg_lo = agg_hi + 4194304;             // 8.39 MB
  // total ws use ~268 MB

  // one-time frag-major converts
  cvt_fr<<<16384, 256, 0, stream>>>(edges, edges_hi, edges_lo, 4194304);
  cvt_fr<<<1024,  256, 0, stream>>>(msg_W, W_hi, W_lo, 262144);
  cvt_fr<<<384,   256, 0, stream>>>(w_ih, wih_hi, wih_lo, 98304);
  cvt_fr<<<384,   256, 0, stream>>>(w_hh, whh_hi, whh_lo, 98304);
  cvt_fr<<<2048,  256, 0, stream>>>(nodes, h_hi, h_lo, 524288);
  bias_sum_k<<<1, 512, 0, stream>>>(msg_b, bsum);

  for (int step = 0; step < 2; ++step) {
    // G1: hWT[b*8+r][e,j] = sum_d W[r][e,d] * h[b][j,d]  (split x split)
    gemm_dr<1, 1, 0><<<dim3(4, 4, 128), 256, 0, stream>>>(
        W_hi, W_lo, h_hi, h_lo, hWT_hi, hWT_lo, nullptr, nullptr,
        512, 1, 0L, 0L, 8, 262144L, 0L, 0L, 262144L, 262144L, 2097152L);
    // G2: split-K x4 (z = b*4+q), R=2; flat grid + XCD swizzle
    gemm_dr<1, 1, 1><<<dim3(1024, 1, 1), 256, 0, stream>>>(
        edges_hi, edges_lo, hWT_hi, hWT_lo, Phi, Plo, nullptr, nullptr,
        512, 2, 262144L, 262144L, 4, 524288L, 2097152L, 524288L, 2097152L,
        4194304L, 262144L);
    // reduce: agg = sum_q (Phi+Plo) + bsum -> frag-major hi/lo
    reduce_agg4<<<4096, 256, 0, stream>>>(Phi, Plo, bsum, agg_hi, agg_lo);
    // G3: gi = agg @ w_ih^T + b_ih  (split-A, fp32 linear out)
    gemm_dr<1, 0, 0><<<dim3(12, 64, 1), 256, 0, stream>>>(
        agg_hi, agg_lo, wih_hi, nullptr, nullptr, nullptr, gi, b_ih,
        1536, 1, 0L, 0L, 1, 0L, 0L, 0L, 0L, 0L, 0L);
    // G4: gh = h @ w_hh^T + b_hh  (single, fp32 linear out)
    gemm_dr<0, 0, 0><<<dim3(12, 64, 1), 256, 0, stream>>>(
        h_hi, nullptr, whh_hi, nullptr, nullptr, nullptr, gh, b_hh,
        1536, 1, 0L, 0L, 1, 0L, 0L, 0L, 0L, 0L, 0L);
    // GRU update -> h hi/lo frag-major (in-place safe)
    gru_k<<<2048, 256, 0, stream>>>(gi, gh, step ? nullptr : nodes, h_hi, h_lo);
  }
  mean_k<<<16, 512, 0, stream>>>(h_hi, h_lo, out);
}

// Round 7
// 809.651 us; speedup vs baseline: 1.3769x; 1.1858x over previous
//
#include <hip/hip_runtime.h>

typedef _Float16 f16;
typedef __attribute__((ext_vector_type(8))) _Float16 half8;
typedef __attribute__((ext_vector_type(4))) float f32x4;

struct f16x4 { f16 a, b, c, d; };

// frag-major layout for tensor[row][k] with K=512:
//   flat f16 idx = (rt*16 + kc)*512 + l*8 + e
//   row = rt*16 + (l&15), k = kc*32 + (l>>4)*8 + e

// ---------------- fp32 -> frag-major f16 hi/lo split ----------------
__global__ void cvt_fr(const float* __restrict__ in, f16* __restrict__ hi,
                       f16* __restrict__ lo, int n_units) {
  const int u = blockIdx.x * blockDim.x + threadIdx.x;
  if (u >= n_units) return;
  const int l = u & 63, kc = (u >> 6) & 15, rt = u >> 10;
  const long ibase = (long)(rt * 16 + (l & 15)) * 512 + kc * 32 + ((l >> 4) << 3);
  const float4 v0 = *(const float4*)(in + ibase);
  const float4 v1 = *(const float4*)(in + ibase + 4);
  const float v[8] = {v0.x, v0.y, v0.z, v0.w, v1.x, v1.y, v1.z, v1.w};
  half8 h, lw;
#pragma unroll
  for (int e = 0; e < 8; ++e) {
    h[e] = (f16)v[e];
    lw[e] = (f16)(v[e] - (float)h[e]);
  }
  *(half8*)(hi + (long)u * 8) = h;
  *(half8*)(lo + (long)u * 8) = lw;
}

// ---------------- fp32 -> frag-major f16 (hi only) ----------------
__global__ void cvt_fr1(const float* __restrict__ in, f16* __restrict__ hi,
                        int n_units) {
  const int u = blockIdx.x * blockDim.x + threadIdx.x;
  if (u >= n_units) return;
  const int l = u & 63, kc = (u >> 6) & 15, rt = u >> 10;
  const long ibase = (long)(rt * 16 + (l & 15)) * 512 + kc * 32 + ((l >> 4) << 3);
  const float4 v0 = *(const float4*)(in + ibase);
  const float4 v1 = *(const float4*)(in + ibase + 4);
  const float v[8] = {v0.x, v0.y, v0.z, v0.w, v1.x, v1.y, v1.z, v1.w};
  half8 h;
#pragma unroll
  for (int e = 0; e < 8; ++e) h[e] = (f16)v[e];
  *(half8*)(hi + (long)u * 8) = h;
}

// ---------------- bias_sum[e] = sum_r msg_b[r,e] ----------------
__global__ void bias_sum_k(const float* __restrict__ msg_b, float* __restrict__ bs) {
  int e = threadIdx.x;  // 512 threads
  float s = 0.f;
  for (int r = 0; r < 8; ++r) s += msg_b[r * 512 + e];
  bs[e] = s;
}

// ---------------- barrier-free direct-register split-f16 MFMA GEMM ----------------
// C[m,n] = sum_{r,k} A_r[m,k]*B_r[n,k]; A,B frag-major (K=512/r-slice).
// acc += Ah*Bh [+Ah*Bl if SB] [+Al*Bh if SA]. 128x128 tile, 4 waves 2x2.
// K-loop: fragments global->VGPR, double-buffered 1 iter ahead, no barriers.
// OUT=1: Chi/Clo frag-major f16 pair (LDS-staged). OUT=0: Cf fp32 linear (+bias).
template <int SA, int SB, int OUT, int SWZ>
__global__ __launch_bounds__(256, 2) void gemm_dr(
    const f16* __restrict__ Ah, const f16* __restrict__ Al,
    const f16* __restrict__ Bh, const f16* __restrict__ Bl,
    f16* __restrict__ Chi, f16* __restrict__ Clo, float* __restrict__ Cf,
    const float* __restrict__ bias, int N, int R, long sAr, long sBr,
    int zdiv, long sAzr, long sAzb, long sBzr, long sBzb,
    long sCzr, long sCzb) {
  __shared__ __align__(16) f16 smem[16384];  // epilogue staging only
  const int tid = threadIdx.x;
  int bx, by, z;
  if constexpr (SWZ) {
    const int l = blockIdx.x;
    const int xcd = l & 7, m2 = l >> 3, zq = m2 >> 4, t = m2 & 15;
    z = (zq << 3) | xcd; bx = t & 3; by = t >> 2;
  } else {
    bx = blockIdx.x; by = blockIdx.y; z = blockIdx.z;
  }
  const int zr = z % zdiv, zb = z / zdiv;
  const int lane = tid & 63;
  const int w = tid >> 6;
  const int wm = (w & 1) << 6;
  const int wn = (w >> 1) << 6;

  const f16* pAh = Ah + (long)zr * sAzr + (long)zb * sAzb +
                   (long)(by * 8 + (wm >> 4)) * 8192 + lane * 8;
  const f16* pBh = Bh + (long)zr * sBzr + (long)zb * sBzb +
                   (long)(bx * 8 + (wn >> 4)) * 8192 + lane * 8;
  const f16* pAl = SA ? (Al + (pAh - Ah)) : nullptr;
  const f16* pBl = SB ? (Bl + (pBh - Bh)) : nullptr;
  const long cbase = (long)zr * sCzr + (long)zb * sCzb;

  f32x4 acc[4][4];
#pragma unroll
  for (int i = 0; i < 4; ++i)
#pragma unroll
    for (int j = 0; j < 4; ++j) acc[i][j] = (f32x4){0.f, 0.f, 0.f, 0.f};

  half8 fAh[2][4], fAl[2][4], fBh[2][4], fBl[2][4];
  const int NIT = R * 16;

  auto LD = [&](int bf, int ii) {
    const int r_ = ii >> 4, kc_ = ii & 15;
    const long oa = (long)r_ * sAr + kc_ * 512;
    const long ob = (long)r_ * sBr + kc_ * 512;
#pragma unroll
    for (int t = 0; t < 4; ++t) {
      fAh[bf][t] = *(const half8*)(pAh + t * 8192 + oa);
      if constexpr (SA) fAl[bf][t] = *(const half8*)(pAl + t * 8192 + oa);
      fBh[bf][t] = *(const half8*)(pBh + t * 8192 + ob);
      if constexpr (SB) fBl[bf][t] = *(const half8*)(pBl + t * 8192 + ob);
    }
  };
  auto MM = [&](int bf) {
#pragma unroll
    for (int mt = 0; mt < 4; ++mt)
#pragma unroll
      for (int nt = 0; nt < 4; ++nt) {
        acc[mt][nt] = __builtin_amdgcn_mfma_f32_16x16x32_f16(
            fAh[bf][mt], fBh[bf][nt], acc[mt][nt], 0, 0, 0);
        if constexpr (SB)
          acc[mt][nt] = __builtin_amdgcn_mfma_f32_16x16x32_f16(
              fAh[bf][mt], fBl[bf][nt], acc[mt][nt], 0, 0, 0);
        if constexpr (SA)
          acc[mt][nt] = __builtin_amdgcn_mfma_f32_16x16x32_f16(
              fAl[bf][mt], fBh[bf][nt], acc[mt][nt], 0, 0, 0);
      }
  };

  LD(0, 0);
  for (int i = 0; i < NIT; i += 2) {
    if (i + 1 < NIT) LD(1, i + 1);
    MM(0);
    if (i + 2 < NIT) LD(0, i + 2);
    if (i + 1 < NIT) MM(1);
  }

  // epilogue: C/D layout col = lane&15, row = (lane>>4)*4 + v  [m89-verified]
  const int l15 = lane & 15;
  const int rb = (lane >> 4) << 2;
  if constexpr (OUT) {
    // frag-major f16 hi/lo pair out via LDS re-stage (swizzle pg=(col>>3)^(row&15))
    // pass 1: hi (turn acc into residual)
#pragma unroll
    for (int nt = 0; nt < 4; ++nt) {
      const int col = wn + nt * 16 + l15;
#pragma unroll
      for (int mt = 0; mt < 4; ++mt)
#pragma unroll
        for (int v = 0; v < 4; ++v) {
          const int row = wm + mt * 16 + rb + v;
          const float cval = acc[mt][nt][v];
          const f16 h = (f16)cval;
          smem[row * 128 + ((col >> 3) ^ (row & 15)) * 8 + (col & 7)] = h;
          acc[mt][nt][v] = cval - (float)h;
        }
    }
    __syncthreads();
#pragma unroll
    for (int i2 = 0; i2 < 8; ++i2) {
      const int u = i2 * 256 + tid;
      const int ul = u & 63, kc_loc = (u >> 6) & 3, rt_loc = u >> 8;
      const int row = rt_loc * 16 + (ul & 15);
      const int gcol = kc_loc * 4 + (ul >> 4);
      const int4 vv = *(const int4*)&smem[row * 128 + ((gcol ^ (row & 15)) << 3)];
      *(int4*)&Chi[cbase + ((long)(by * 8 + rt_loc) * 16 + bx * 4 + kc_loc) * 512 + ul * 8] = vv;
    }
    __syncthreads();
    // pass 2: lo
#pragma unroll
    for (int nt = 0; nt < 4; ++nt) {
      const int col = wn + nt * 16 + l15;
#pragma unroll
      for (int mt = 0; mt < 4; ++mt)
#pragma unroll
        for (int v = 0; v < 4; ++v) {
          const int row = wm + mt * 16 + rb + v;
          smem[row * 128 + ((col >> 3) ^ (row & 15)) * 8 + (col & 7)] = (f16)acc[mt][nt][v];
        }
    }
    __syncthreads();
#pragma unroll
    for (int i2 = 0; i2 < 8; ++i2) {
      const int u = i2 * 256 + tid;
      const int ul = u & 63, kc_loc = (u >> 6) & 3, rt_loc = u >> 8;
      const int row = rt_loc * 16 + (ul & 15);
      const int gcol = kc_loc * 4 + (ul >> 4);
      const int4 vv = *(const int4*)&smem[row * 128 + ((gcol ^ (row & 15)) << 3)];
      *(int4*)&Clo[cbase + ((long)(by * 8 + rt_loc) * 16 + bx * 4 + kc_loc) * 512 + ul * 8] = vv;
    }
  } else {
    // fp32 direct output (linear rows x N)
#pragma unroll
    for (int nt = 0; nt < 4; ++nt) {
      const int col = bx * 128 + wn + nt * 16 + l15;
      const float bv = bias ? bias[col] : 0.f;
#pragma unroll
      for (int mt = 0; mt < 4; ++mt) {
        const long rowbase = (long)(by * 128 + wm + mt * 16 + rb) * N + col;
#pragma unroll
        for (int v = 0; v < 4; ++v)
          Cf[cbase + rowbase + (long)v * N] = acc[mt][nt][v] + bv;
      }
    }
  }
}

// ---------------- split-K x4 reduce (frag-major): agg = sum_q(Phi+Plo)+bsum ----------------
__global__ void reduce_agg4(const f16* __restrict__ Phi, const f16* __restrict__ Plo,
                            const float* __restrict__ bsum,
                            f16* __restrict__ hi, f16* __restrict__ lo) {
  const long i = ((long)blockIdx.x * blockDim.x + threadIdx.x) * 4;  // 4096x256 blocks
  const int li = (int)i;
  const int l = (li >> 3) & 63, kc = (li >> 9) & 15;
  const int e0 = kc * 32 + ((l >> 4) << 3) + (li & 4);
  const float4 b = *(const float4*)(bsum + e0);
  float v0 = b.x, v1 = b.y, v2 = b.z, v3 = b.w;
#pragma unroll
  for (int q = 0; q < 4; ++q) {
    const long o = (long)q * 4194304 + i;
    const f16x4 ph = *(const f16x4*)(Phi + o);
    const f16x4 pl = *(const f16x4*)(Plo + o);
    v0 += (float)ph.a + (float)pl.a;
    v1 += (float)ph.b + (float)pl.b;
    v2 += (float)ph.c + (float)pl.c;
    v3 += (float)ph.d + (float)pl.d;
  }
  f16x4 h, lw;
  h.a = (f16)v0; lw.a = (f16)(v0 - (float)h.a);
  h.b = (f16)v1; lw.b = (f16)(v1 - (float)h.b);
  h.c = (f16)v2; lw.c = (f16)(v2 - (float)h.c);
  h.d = (f16)v3; lw.d = (f16)(v3 - (float)h.d);
  *(f16x4*)(hi + i) = h;
  *(f16x4*)(lo + i) = lw;
}

// ---------------- GRU elementwise (fp32 gates), h frag-major f16 ----------------
__global__ void gru_k(const float* __restrict__ gi, const float* __restrict__ gh,
                      const float* __restrict__ holdf, f16* __restrict__ hhi) {
  const int u = blockIdx.x * blockDim.x + threadIdx.x;  // 524288 threads
  const int row = u >> 6, d0 = (u & 63) << 3;
  const long gbase = (long)row * 1536 + d0;
  const float4 giR0 = *(const float4*)(gi + gbase),      giR1 = *(const float4*)(gi + gbase + 4);
  const float4 giZ0 = *(const float4*)(gi + gbase + 512), giZ1 = *(const float4*)(gi + gbase + 516);
  const float4 giN0 = *(const float4*)(gi + gbase + 1024), giN1 = *(const float4*)(gi + gbase + 1028);
  const float4 ghR0 = *(const float4*)(gh + gbase),      ghR1 = *(const float4*)(gh + gbase + 4);
  const float4 ghZ0 = *(const float4*)(gh + gbase + 512), ghZ1 = *(const float4*)(gh + gbase + 516);
  const float4 ghN0 = *(const float4*)(gh + gbase + 1024), ghN1 = *(const float4*)(gh + gbase + 1028);
  const float irv[8] = {giR0.x, giR0.y, giR0.z, giR0.w, giR1.x, giR1.y, giR1.z, giR1.w};
  const float izv[8] = {giZ0.x, giZ0.y, giZ0.z, giZ0.w, giZ1.x, giZ1.y, giZ1.z, giZ1.w};
  const float inv[8] = {giN0.x, giN0.y, giN0.z, giN0.w, giN1.x, giN1.y, giN1.z, giN1.w};
  const float hrv[8] = {ghR0.x, ghR0.y, ghR0.z, ghR0.w, ghR1.x, ghR1.y, ghR1.z, ghR1.w};
  const float hzv[8] = {ghZ0.x, ghZ0.y, ghZ0.z, ghZ0.w, ghZ1.x, ghZ1.y, ghZ1.z, ghZ1.w};
  const float hnv[8] = {ghN0.x, ghN0.y, ghN0.z, ghN0.w, ghN1.x, ghN1.y, ghN1.z, ghN1.w};
  const long hflat = (long)(row >> 4) * 8192 + (d0 >> 5) * 512 +
                     ((row & 15) + (((d0 >> 3) & 3) << 4)) * 8;
  half8 hh8;
  if (!holdf) hh8 = *(const half8*)(hhi + hflat);
  half8 oh;
#pragma unroll
  for (int e = 0; e < 8; ++e) {
    const float h = holdf ? holdf[(long)row * 512 + d0 + e] : (float)hh8[e];
    const float r = 1.f / (1.f + __expf(-(irv[e] + hrv[e])));
    const float zg = 1.f / (1.f + __expf(-(izv[e] + hzv[e])));
    const float nt = tanhf(inv[e] + r * hnv[e]);
    const float o = (1.f - zg) * nt + zg * h;
    oh[e] = (f16)o;
  }
  *(half8*)(hhi + hflat) = oh;
}

// ---------------- mean over nodes (h frag-major) ----------------
__global__ void mean_k(const f16* __restrict__ hhi, float* __restrict__ out) {
  const int b = blockIdx.x;   // 16
  const int d = threadIdx.x;  // 512
  const long base = (long)b * 262144 + (d >> 5) * 512 + (((d >> 3) & 3) << 4) * 8 + (d & 7);
  float s = 0.f;
  for (int n = 0; n < 512; ++n) {
    const long j = base + (long)(n >> 4) * 8192 + (n & 15) * 8;
    s += (float)hhi[j];
  }
  out[b * 512 + d] = s * (1.f / 512.f);
}

extern "C" void kernel_launch(void* const* d_in, const int* in_sizes, int n_in,
                              void* d_out, int out_size, void* d_ws, size_t ws_size,
                              hipStream_t stream) {
  const float* nodes = (const float*)d_in[0];  // [16,512,512]
  const float* edges = (const float*)d_in[1];  // [16,8,512,512]
  const float* msg_W = (const float*)d_in[2];  // [8,512,512]
  const float* msg_b = (const float*)d_in[3];  // [8,512]
  const float* w_ih  = (const float*)d_in[4];  // [1536,512]
  const float* w_hh  = (const float*)d_in[5];  // [1536,512]
  const float* b_ih  = (const float*)d_in[6];  // [1536]
  const float* b_hh  = (const float*)d_in[7];  // [1536]
  float* out = (float*)d_out;                  // [16,512]

  char* ws = (char*)d_ws;
  size_t off = 0;
  auto alloc = [&](size_t bytes) -> char* {
    char* p = ws + off;
    off += (bytes + 1023) & ~(size_t)1023;
    return p;
  };
  f16* edges_hi = (f16*)alloc(33554432ull * 2);  // hi only (edges_lo dropped)
  f16* W_hi     = (f16*)alloc(2097152ull * 2);
  f16* W_lo     = (f16*)alloc(2097152ull * 2);
  f16* wih_hi   = (f16*)alloc(786432ull * 2);
  f16* whh_hi   = (f16*)alloc(786432ull * 2);
  f16* h_hi     = (f16*)alloc(4194304ull * 2);   // hi only (h_lo dropped)
  f16* hWT_hi   = (f16*)alloc(33554432ull * 2);  // head: gi fp32 after G3; tail: agg_hi/lo
  f16* hWT_lo   = (f16*)alloc(33554432ull * 2);  // head: gh fp32 after G4
  f16* Phi      = (f16*)alloc(16777216ull * 2);  // split-K x4 partial hi [q][b][frag-major]
  f16* Plo      = (f16*)alloc(16777216ull * 2);
  float* bsum   = (float*)alloc(512 * 4);
  float* gi = (float*)hWT_hi;                 // 50.33 MB
  float* gh = (float*)hWT_lo;                 // 50.33 MB
  f16* agg_hi = hWT_hi + 25165824;            // 8.39 MB
  f16* agg_lo = agg_hi + 4194304;             // 8.39 MB
  // total ws use ~205 MB

  // one-time frag-major converts
  cvt_fr1<<<16384, 256, 0, stream>>>(edges, edges_hi, 4194304);
  cvt_fr<<<1024,  256, 0, stream>>>(msg_W, W_hi, W_lo, 262144);
  cvt_fr1<<<384,  256, 0, stream>>>(w_ih, wih_hi, 98304);
  cvt_fr1<<<384,  256, 0, stream>>>(w_hh, whh_hi, 98304);
  cvt_fr1<<<2048, 256, 0, stream>>>(nodes, h_hi, 524288);
  bias_sum_k<<<1, 512, 0, stream>>>(msg_b, bsum);

  for (int step = 0; step < 2; ++step) {
    // G1: hWT[b*8+r][e,j] = sum_d W[r][e,d] * h[b][j,d]
    //     split-A (W hi/lo) x single-B (h hi); f16-pair out
    gemm_dr<1, 0, 1, 0><<<dim3(4, 4, 128), 256, 0, stream>>>(
        W_hi, W_lo, h_hi, nullptr, hWT_hi, hWT_lo, nullptr, nullptr,
        512, 1, 0L, 0L, 8, 262144L, 0L, 0L, 262144L, 262144L, 2097152L);
    // G2: split-K x4 (z = b*4+q), R=2; flat grid + XCD swizzle
    //     single-A (edges hi) x split-B (hWT hi/lo); f16-pair partials out
    gemm_dr<0, 1, 1, 1><<<dim3(1024, 1, 1), 256, 0, stream>>>(
        edges_hi, nullptr, hWT_hi, hWT_lo, Phi, Plo, nullptr, nullptr,
        512, 2, 262144L, 262144L, 4, 524288L, 2097152L, 524288L, 2097152L,
        4194304L, 262144L);
    // reduce: agg = sum_q (Phi+Plo) + bsum -> frag-major hi/lo
    reduce_agg4<<<4096, 256, 0, stream>>>(Phi, Plo, bsum, agg_hi, agg_lo);
    // G3: gi = agg @ w_ih^T + b_ih  (split-A, fp32 linear out)
    gemm_dr<1, 0, 0, 0><<<dim3(12, 64, 1), 256, 0, stream>>>(
        agg_hi, agg_lo, wih_hi, nullptr, nullptr, nullptr, gi, b_ih,
        1536, 1, 0L, 0L, 1, 0L, 0L, 0L, 0L, 0L, 0L);
    // G4: gh = h @ w_hh^T + b_hh  (single, fp32 linear out)
    gemm_dr<0, 0, 0, 0><<<dim3(12, 64, 1), 256, 0, stream>>>(
        h_hi, nullptr, whh_hi, nullptr, nullptr, nullptr, gh, b_hh,
        1536, 1, 0L, 0L, 1, 0L, 0L, 0L, 0L, 0L, 0L);
    // GRU update -> h_hi frag-major (in-place safe)
    gru_k<<<2048, 256, 0, stream>>>(gi, gh, step ? nullptr : nodes, h_hi);
  }
  mean_k<<<16, 512, 0, stream>>>(h_hi, out);
}